// Round 10
// baseline (883.345 us; speedup 1.0000x reference)
//
#include <hip/hip_runtime.h>
#include <hip/hip_fp16.h>
#include <cstdint>
#include <cstddef>

#define IN_DIM 128
#define HID    128
#define NG     20
#define T      4096        // edges per binsort1 block
#define MAXB   400         // max coarse bins (N <= 102400)

typedef _Float16 half8 __attribute__((ext_vector_type(8)));
typedef _Float16 half4 __attribute__((ext_vector_type(4)));
typedef float    f32x4 __attribute__((ext_vector_type(4)));

__global__ void zero_ints(int* __restrict__ a, int n) {
  int i = blockIdx.x * blockDim.x + threadIdx.x;
  if (i < n) a[i] = 0;
}

// ============ level 1: block-local sort into coarse bins (256 nodes/bin) ============
// INSTRUMENTED: body repeats `reps` times (idempotent; bintot only on last rep)
// so per-dispatch dur = reps * true stage time -> visible in rocprof top-5.
__global__ __launch_bounds__(256) void binsort1(const int* __restrict__ src,
    const int* __restrict__ dst, int* __restrict__ tmp, int* __restrict__ bofs,
    int* __restrict__ bintot, int NBC, int E, int reps) {
  __shared__ int lhist[MAXB];
  __shared__ int lscan[512];
  __shared__ int lcur[MAXB];
  __shared__ int sbuf[T];
  int tid = threadIdx.x;
  int tile0 = blockIdx.x * T;
  int m = E - tile0; if (m > T) m = T;

  for (int rep = 0; rep < reps; ++rep) {
    __syncthreads();
    for (int i = tid; i < NBC; i += 256) lhist[i] = 0;
    __syncthreads();

    int dreg[16];
#pragma unroll
    for (int j = 0; j < 16; ++j) {
      int idx = j * 256 + tid;
      dreg[j] = -1;
      if (idx < m) {
        int d = dst[tile0 + idx];
        dreg[j] = d;
        atomicAdd(&lhist[d >> 8], 1);
      }
    }
    __syncthreads();

    int v0 = (tid < NBC) ? lhist[tid] : 0;
    int v1 = (256 + tid < NBC) ? lhist[256 + tid] : 0;
    lscan[tid] = v0; lscan[256 + tid] = v1;
    __syncthreads();
    for (int o = 1; o < 512; o <<= 1) {
      int a0 = (tid >= o) ? lscan[tid - o] : 0;
      int a1 = (256 + tid >= o) ? lscan[256 + tid - o] : 0;
      __syncthreads();
      lscan[tid] += a0; lscan[256 + tid] += a1;
      __syncthreads();
    }
    if (tid < NBC)       lcur[tid]       = lscan[tid] - v0;
    if (256 + tid < NBC) lcur[256 + tid] = lscan[256 + tid] - v1;
    __syncthreads();

    int ST = NBC + 1;
    for (int i = tid; i < NBC; i += 256) bofs[(size_t)blockIdx.x * ST + i] = lcur[i];
    if (tid == 0) bofs[(size_t)blockIdx.x * ST + NBC] = m;
    if (rep == reps - 1)
      for (int i = tid; i < NBC; i += 256)
        if (lhist[i]) atomicAdd(&bintot[i], lhist[i]);
    __syncthreads();

#pragma unroll
    for (int j = 0; j < 16; ++j) {
      int idx = j * 256 + tid;
      if (idx < m) {
        int d = dreg[j];
        int s = src[tile0 + idx];
        int slot = atomicAdd(&lcur[d >> 8], 1);
        sbuf[slot] = ((d & 255) << 17) | s;
      }
    }
    __syncthreads();

    int nv = m >> 2;
    int4* out4 = (int4*)(tmp + tile0);
    const int4* sb4 = (const int4*)sbuf;
    for (int i = tid; i < nv; i += 256) out4[i] = sb4[i];
    for (int i = (nv << 2) + tid; i < m; i += 256) tmp[tile0 + i] = sbuf[i];
  }
}

// ============ scan bin totals -> bin bases (1 block) ============
__global__ __launch_bounds__(512) void binscan(const int* __restrict__ bintot,
                                               int* __restrict__ binbase, int NBC) {
  __shared__ int s[512];
  int tid = threadIdx.x;
  int v = (tid < NBC) ? bintot[tid] : 0;
  s[tid] = v;
  __syncthreads();
  for (int o = 1; o < 512; o <<= 1) {
    int t = (tid >= o) ? s[tid - o] : 0;
    __syncthreads();
    s[tid] += t;
    __syncthreads();
  }
  if (tid < NBC) binbase[tid] = s[tid] - v;
}

// ============ level 2: one block per coarse bin -> final CSR + node meta ============
// INSTRUMENTED: idempotent rep loop (same semantics every rep).
__global__ __launch_bounds__(512) void binsort2(const int* __restrict__ tmp,
    const int* __restrict__ bofs, const int* __restrict__ binbase,
    int* __restrict__ csrc, int* __restrict__ cnt, float* __restrict__ dis,
    int* __restrict__ offs, int NBC, int nblk, int N, int reps) {
  __shared__ int lcnt[256];
  __shared__ int lsc[256];
  __shared__ int lcur2[256];
  int b = blockIdx.x;
  int tid = threadIdx.x;
  int ST = NBC + 1;

  for (int rep = 0; rep < reps; ++rep) {
    __syncthreads();
    if (tid < 256) lcnt[tid] = 0;
    __syncthreads();
    for (int r = tid; r < nblk; r += 512) {
      int s = bofs[(size_t)r * ST + b];
      int e2 = bofs[(size_t)r * ST + b + 1];
      int base = r * T;
      for (int k = s; k < e2; ++k)
        atomicAdd(&lcnt[tmp[base + k] >> 17], 1);
    }
    __syncthreads();
    if (tid < 256) lsc[tid] = lcnt[tid];
    __syncthreads();
    for (int o = 1; o < 256; o <<= 1) {
      int t = 0;
      if (tid < 256 && tid >= o) t = lsc[tid - o];
      __syncthreads();
      if (tid < 256) lsc[tid] += t;
      __syncthreads();
    }
    int gbase = binbase[b];
    if (tid < 256) {
      int excl = lsc[tid] - lcnt[tid];
      lcur2[tid] = gbase + excl;
      int node = (b << 8) + tid;
      if (node < N) {
        cnt[node] = lcnt[tid];
        dis[node] = rsqrtf((float)lcnt[tid] + 1.0f);
        offs[node] = gbase + excl;
      }
    }
    __syncthreads();
    for (int r = tid; r < nblk; r += 512) {
      int s = bofs[(size_t)r * ST + b];
      int e2 = bofs[(size_t)r * ST + b + 1];
      int base = r * T;
      for (int k = s; k < e2; ++k) {
        int rec = tmp[base + k];
        int pos = atomicAdd(&lcur2[rec >> 17], 1);
        csrc[pos] = rec & 0x1FFFF;
      }
    }
  }
}

// ============ MFMA GEMM, f16 out: C16[M,128] = A[M,128] @ B[128,128] ============
// INSTRUMENTED: idempotent rep loop.
template<bool F16IN>
__global__ __launch_bounds__(256) void gemm128_mfma(const void* __restrict__ Av,
                                                    const float* __restrict__ B,
                                                    __half* __restrict__ C, int M,
                                                    int reps) {
  __shared__ _Float16 sA[128][136];
  const int tid = threadIdx.x;
  const int m0 = blockIdx.x * 128;
  const int wave = tid >> 6, lane = tid & 63;
  const int nbase = wave << 5;
  const int lrow = lane & 15;
  const int khi  = lane >> 4;
  const float* wcol = B + nbase + lrow;

  for (int rep = 0; rep < reps; ++rep) {
    __syncthreads();
    float bA[2][8], bB[2][8];
#pragma unroll
    for (int nf = 0; nf < 2; ++nf)
#pragma unroll
      for (int rr = 0; rr < 8; ++rr)
        bA[nf][rr] = wcol[(size_t)(khi * 8 + rr) * 128 + nf * 16];

    if constexpr (F16IN) {
      const __half* A = (const __half*)Av;
#pragma unroll
      for (int q = 0; q < 8; ++q) {
        int idx = q * 256 + tid;
        int r = idx >> 4;
        int cc = (idx & 15) << 3;
        half8 hv = {};
        if (m0 + r < M) hv = *(const half8*)(A + (size_t)(m0 + r) * 128 + cc);
        *(half8*)(&sA[r][cc]) = hv;
      }
    } else {
      const float* A = (const float*)Av;
#pragma unroll
      for (int q = 0; q < 16; ++q) {
        int idx = q * 256 + tid;
        int r = idx >> 5;
        int cc = (idx & 31) << 2;
        float4 v = make_float4(0.f, 0.f, 0.f, 0.f);
        if (m0 + r < M) v = *(const float4*)(A + (size_t)(m0 + r) * 128 + cc);
        half4 hv;
        hv[0] = (_Float16)v.x; hv[1] = (_Float16)v.y;
        hv[2] = (_Float16)v.z; hv[3] = (_Float16)v.w;
        *(half4*)(&sA[r][cc]) = hv;
      }
    }
    __syncthreads();

    f32x4 acc[8][2];
#pragma unroll
    for (int mf = 0; mf < 8; ++mf)
#pragma unroll
      for (int nf = 0; nf < 2; ++nf) acc[mf][nf] = (f32x4){0.f, 0.f, 0.f, 0.f};

    auto loadB = [&](float (&dst)[2][8], int ks) {
#pragma unroll
      for (int nf = 0; nf < 2; ++nf)
#pragma unroll
        for (int rr = 0; rr < 8; ++rr)
          dst[nf][rr] = wcol[(size_t)(ks * 32 + khi * 8 + rr) * 128 + nf * 16];
    };
    half8 bf0, bf1;
    auto cvtB = [&](float (&s)[2][8]) {
#pragma unroll
      for (int rr = 0; rr < 8; ++rr) {
        bf0[rr] = (_Float16)s[0][rr];
        bf1[rr] = (_Float16)s[1][rr];
      }
    };
    auto mfmas = [&](int ks) {
#pragma unroll
      for (int mf = 0; mf < 8; ++mf) {
        half8 a = *(const half8*)(&sA[mf * 16 + lrow][khi * 8 + ks * 32]);
        acc[mf][0] = __builtin_amdgcn_mfma_f32_16x16x32_f16(a, bf0, acc[mf][0], 0, 0, 0);
        acc[mf][1] = __builtin_amdgcn_mfma_f32_16x16x32_f16(a, bf1, acc[mf][1], 0, 0, 0);
      }
    };
    cvtB(bA); loadB(bB, 1); mfmas(0);
    cvtB(bB); loadB(bA, 2); mfmas(1);
    cvtB(bA); loadB(bB, 3); mfmas(2);
    cvtB(bB);               mfmas(3);

#pragma unroll
    for (int mf = 0; mf < 8; ++mf) {
      int r0 = mf * 16 + khi * 4;
#pragma unroll
      for (int nf = 0; nf < 2; ++nf) {
        int ccol = nbase + nf * 16 + lrow;
#pragma unroll
        for (int reg = 0; reg < 4; ++reg) {
          int r = m0 + r0 + reg;
          if (r < M) C[(size_t)r * 128 + ccol] = __float2half(acc[mf][nf][reg]);
        }
      }
    }
  }
}

// ============ aggregation: two nodes per wave, interleaved gather chains ============
// PROVEN (115 us @ 3.75 TB/s pattern roofline). Not instrumented (already visible).
template<typename OutT>
__global__ __launch_bounds__(256) void agg_kernel(const __half* __restrict__ h,
    const int* __restrict__ csrc,
    const int* __restrict__ offs, const int* __restrict__ cnt,
    const float* __restrict__ dis, const float* __restrict__ bias,
    OutT* __restrict__ out, int n) {
  int wave = threadIdx.x >> 6;
  int lane = threadIdx.x & 63;
  int i0 = (blockIdx.x * 4 + wave) * 2;
  if (i0 >= n) return;
  int i1 = i0 + 1;
  bool has1 = i1 < n;
  int c = lane * 2;

  int st0 = offs[i0];
  int m0  = cnt[i0];
  float d0 = dis[i0];
  int st1 = 0, m1 = 0;
  float d1 = 0.f;
  if (has1) { st1 = offs[i1]; m1 = cnt[i1]; d1 = dis[i1]; }

  float ax0 = 0.f, ay0 = 0.f, ax1 = 0.f, ay1 = 0.f;
  int mMax = m0 > m1 ? m0 : m1;

  for (int base = 0; base < mMax; base += 64) {
    int mcA = m0 - base; mcA = mcA < 0 ? 0 : (mcA > 64 ? 64 : mcA);
    int mcB = m1 - base; mcB = mcB < 0 ? 0 : (mcB > 64 ? 64 : mcB);
    int mc = mcA > mcB ? mcA : mcB;

    int sA = 0, sB = 0;
    float wA = 0.f, wB = 0.f;
    if (lane < mcA) sA = csrc[st0 + base + lane];
    if (lane < mcB) sB = csrc[st1 + base + lane];
    if (lane < mcA) wA = dis[sA] * d0;
    if (lane < mcB) wB = dis[sB] * d1;

    int j = 0;
    for (; j + 4 <= mc; j += 4) {
      int   a0 = __shfl(sA, j);
      int   a1 = __shfl(sA, j + 1);
      int   a2 = __shfl(sA, j + 2);
      int   a3 = __shfl(sA, j + 3);
      int   b0 = __shfl(sB, j);
      int   b1 = __shfl(sB, j + 1);
      int   b2 = __shfl(sB, j + 2);
      int   b3 = __shfl(sB, j + 3);
      float u0 = __shfl(wA, j);
      float u1 = __shfl(wA, j + 1);
      float u2 = __shfl(wA, j + 2);
      float u3 = __shfl(wA, j + 3);
      float v0 = __shfl(wB, j);
      float v1 = __shfl(wB, j + 1);
      float v2 = __shfl(wB, j + 2);
      float v3 = __shfl(wB, j + 3);
      float2 hA0 = __half22float2(*(const __half2*)(h + ((size_t)a0 << 7) + c));
      float2 hA1 = __half22float2(*(const __half2*)(h + ((size_t)a1 << 7) + c));
      float2 hA2 = __half22float2(*(const __half2*)(h + ((size_t)a2 << 7) + c));
      float2 hA3 = __half22float2(*(const __half2*)(h + ((size_t)a3 << 7) + c));
      float2 hB0 = __half22float2(*(const __half2*)(h + ((size_t)b0 << 7) + c));
      float2 hB1 = __half22float2(*(const __half2*)(h + ((size_t)b1 << 7) + c));
      float2 hB2 = __half22float2(*(const __half2*)(h + ((size_t)b2 << 7) + c));
      float2 hB3 = __half22float2(*(const __half2*)(h + ((size_t)b3 << 7) + c));
      ax0 = fmaf(hA0.x, u0, ax0); ay0 = fmaf(hA0.y, u0, ay0);
      ax0 = fmaf(hA1.x, u1, ax0); ay0 = fmaf(hA1.y, u1, ay0);
      ax0 = fmaf(hA2.x, u2, ax0); ay0 = fmaf(hA2.y, u2, ay0);
      ax0 = fmaf(hA3.x, u3, ax0); ay0 = fmaf(hA3.y, u3, ay0);
      ax1 = fmaf(hB0.x, v0, ax1); ay1 = fmaf(hB0.y, v0, ay1);
      ax1 = fmaf(hB1.x, v1, ax1); ay1 = fmaf(hB1.y, v1, ay1);
      ax1 = fmaf(hB2.x, v2, ax1); ay1 = fmaf(hB2.y, v2, ay1);
      ax1 = fmaf(hB3.x, v3, ax1); ay1 = fmaf(hB3.y, v3, ay1);
    }
    for (; j < mc; ++j) {
      int   a0 = __shfl(sA, j);
      int   b0 = __shfl(sB, j);
      float u0 = __shfl(wA, j);
      float v0 = __shfl(wB, j);
      float2 hA0 = __half22float2(*(const __half2*)(h + ((size_t)a0 << 7) + c));
      float2 hB0 = __half22float2(*(const __half2*)(h + ((size_t)b0 << 7) + c));
      ax0 = fmaf(hA0.x, u0, ax0); ay0 = fmaf(hA0.y, u0, ay0);
      ax1 = fmaf(hB0.x, v0, ax1); ay1 = fmaf(hB0.y, v0, ay1);
    }
  }

  float2 bv = *(const float2*)(bias + c);
  {
    float dd = d0 * d0;
    float2 hs = __half22float2(*(const __half2*)(h + ((size_t)i0 << 7) + c));
    float vx = fmaxf(fmaf(hs.x, dd, ax0) + bv.x, 0.f);
    float vy = fmaxf(fmaf(hs.y, dd, ay0) + bv.y, 0.f);
    if constexpr (sizeof(OutT) == 2) {
      *(__half2*)((__half*)out + (size_t)i0 * 128 + c) = __floats2half2_rn(vx, vy);
    } else {
      *(float2*)((float*)out + (size_t)i0 * 128 + c) = make_float2(vx, vy);
    }
  }
  if (has1) {
    float dd = d1 * d1;
    float2 hs = __half22float2(*(const __half2*)(h + ((size_t)i1 << 7) + c));
    float vx = fmaxf(fmaf(hs.x, dd, ax1) + bv.x, 0.f);
    float vy = fmaxf(fmaf(hs.y, dd, ay1) + bv.y, 0.f);
    if constexpr (sizeof(OutT) == 2) {
      *(__half2*)((__half*)out + (size_t)i1 * 128 + c) = __floats2half2_rn(vx, vy);
    } else {
      *(float2*)((float*)out + (size_t)i1 * 128 + c) = make_float2(vx, vy);
    }
  }
}

// ============ heads: pack 3x[128,20] weights into [128,64] (cols 60..63 zero) ============
__global__ void pack_heads_w(const float* __restrict__ piW, const float* __restrict__ muW,
                             const float* __restrict__ lsW, float* __restrict__ W64) {
  int i = blockIdx.x * 256 + threadIdx.x;
  if (i >= 128 * 64) return;
  int k = i >> 6, j = i & 63;
  float v = 0.f;
  if (j < 20)      v = piW[k * 20 + j];
  else if (j < 40) v = muW[k * 20 + (j - 20)];
  else if (j < 60) v = lsW[k * 20 + (j - 40)];
  W64[i] = v;
}

// ============ fused heads: GEMM [M,128]@[128,64] + bias + softmax(20) + scatter ====
// INSTRUMENTED: idempotent rep loop.
#define KC 64
__global__ __launch_bounds__(256) void heads_fused(const float* __restrict__ A,
    const float* __restrict__ B, const float* __restrict__ pib,
    const float* __restrict__ mub, const float* __restrict__ lsb,
    float* __restrict__ out, int n, int reps) {
  __shared__ float sA[64][KC + 4];
  __shared__ float sB[KC][68];
  __shared__ float sOut[64][68];
  int tid = threadIdx.x;
  int m0 = blockIdx.x * 64;
  int tr = tid >> 4;   // 0..15
  int tc = tid & 15;   // 0..15

  for (int rep = 0; rep < reps; ++rep) {
    __syncthreads();
    float acc[4][4];
#pragma unroll
    for (int i = 0; i < 4; ++i)
#pragma unroll
      for (int j = 0; j < 4; ++j) acc[i][j] = 0.f;

    for (int k0 = 0; k0 < 128; k0 += KC) {
#pragma unroll
      for (int q = 0; q < 4; ++q) {
        int idx = q * 256 + tid;
        int r = idx >> 4;
        int kk = (idx & 15) << 2;
        float4 v = make_float4(0.f, 0.f, 0.f, 0.f);
        if (m0 + r < n) v = *(const float4*)(A + (size_t)(m0 + r) * 128 + k0 + kk);
        *(float4*)(&sA[r][kk]) = v;
      }
#pragma unroll
      for (int q = 0; q < 4; ++q) {
        int idx = q * 256 + tid;
        int kk = idx >> 4;
        int nn = (idx & 15) << 2;
        *(float4*)(&sB[kk][nn]) = *(const float4*)(B + (size_t)(k0 + kk) * 64 + nn);
      }
      __syncthreads();
#pragma unroll 4
      for (int k = 0; k < KC; k += 4) {
        float4 a0 = *(const float4*)(&sA[tr][k]);
        float4 a1 = *(const float4*)(&sA[tr + 16][k]);
        float4 a2 = *(const float4*)(&sA[tr + 32][k]);
        float4 a3 = *(const float4*)(&sA[tr + 48][k]);
#pragma unroll
        for (int u = 0; u < 4; ++u) {
          float4 b = *(const float4*)(&sB[k + u][tc * 4]);
          float av[4] = {((const float*)&a0)[u], ((const float*)&a1)[u],
                         ((const float*)&a2)[u], ((const float*)&a3)[u]};
#pragma unroll
          for (int i = 0; i < 4; ++i) {
            acc[i][0] = fmaf(av[i], b.x, acc[i][0]);
            acc[i][1] = fmaf(av[i], b.y, acc[i][1]);
            acc[i][2] = fmaf(av[i], b.z, acc[i][2]);
            acc[i][3] = fmaf(av[i], b.w, acc[i][3]);
          }
        }
      }
      __syncthreads();
    }

#pragma unroll
    for (int i = 0; i < 4; ++i)
#pragma unroll
      for (int j = 0; j < 4; ++j) sOut[tr + 16 * i][tc * 4 + j] = acc[i][j];
    __syncthreads();

    int wave = tid >> 6, lane = tid & 63;
    size_t nb = (size_t)n * NG;
    for (int t = 0; t < 16; ++t) {
      int rr = wave * 16 + t;
      int node = m0 + rr;
      if (node >= n) break;   // wave-uniform
      float v = 0.f;
      if (lane < 60) {
        v = sOut[rr][lane];
        v += (lane < 20) ? pib[lane] : (lane < 40) ? mub[lane - 20] : lsb[lane - 40];
      }
      float pv = (lane < 20) ? v : -__builtin_inff();
      float mx = pv;
      for (int o = 16; o > 0; o >>= 1) mx = fmaxf(mx, __shfl_down(mx, o, 32));
      mx = __shfl(mx, 0, 32);
      float ev = (lane < 20) ? expf(v - mx) : 0.f;
      float sm = ev;
      for (int o = 16; o > 0; o >>= 1) sm += __shfl_down(sm, o, 32);
      sm = __shfl(sm, 0, 32);
      if (lane < 20)      out[(size_t)node * NG + lane] = ev / sm;
      else if (lane < 40) out[nb + (size_t)node * NG + (lane - 20)] = v;
      else if (lane < 60) out[2 * nb + (size_t)node * NG + (lane - 40)] = v;
    }
  }
}

extern "C" void kernel_launch(void* const* d_in, const int* in_sizes, int n_in,
                              void* d_out, int out_size, void* d_ws, size_t ws_size,
                              hipStream_t stream) {
  const float* x   = (const float*)d_in[0];
  const int*   ei  = (const int*)d_in[1];
  const float* W1  = (const float*)d_in[2];
  const float* b1  = (const float*)d_in[3];
  const float* W2  = (const float*)d_in[4];
  const float* b2  = (const float*)d_in[5];
  const float* piW = (const float*)d_in[6];
  const float* pib = (const float*)d_in[7];
  const float* muW = (const float*)d_in[8];
  const float* mub = (const float*)d_in[9];
  const float* lsW = (const float*)d_in[10];
  const float* lsb = (const float*)d_in[11];
  float* out = (float*)d_out;

  const int N = in_sizes[0] / IN_DIM;
  const int E = in_sizes[1] / 2;
  const int* src = ei;
  const int* dst = ei + E;

  const int NBC  = (N + 255) >> 8;          // 391 coarse bins
  const int nblk = (E + T - 1) / T;         // 782 level-1 blocks
  const int ST   = NBC + 1;

  const int REPS = 3;   // instrumentation: stage dur x3 -> visible in top-5

  // workspace layout
  char* p = (char*)d_ws;
  char* regionH = p;                        p += (size_t)N * HID * sizeof(__half);
  __half* h16  = (__half*)regionH;
  char* regionR = p;                        // tmp -> bufB16 -> bufB (sequential reuse)
  size_t szR = (size_t)N * HID * sizeof(float);
  size_t szT = (size_t)E * sizeof(int);
  p += (szR > szT ? szR : szT);
  int*    tmp    = (int*)regionR;
  __half* bufB16 = (__half*)regionR;
  float*  bufB   = (float*)regionR;
  int*   csrc   = (int*)p;                  p += (size_t)E * sizeof(int);
  int*   bofs   = (int*)p;                  p += (size_t)nblk * ST * sizeof(int);
  int*   bintot = (int*)p;                  p += (size_t)MAXB * sizeof(int);
  int*   binbase= (int*)p;                  p += (size_t)MAXB * sizeof(int);
  int*   cnt    = (int*)p;                  p += (size_t)N * sizeof(int);
  int*   offs   = (int*)p;                  p += (size_t)N * sizeof(int);
  float* dis    = (float*)p;                p += (size_t)N * sizeof(float);
  float* W64    = (float*)p;                p += (size_t)128 * 64 * sizeof(float);

  // ---- CSR build ----
  zero_ints<<<(NBC + 255) / 256, 256, 0, stream>>>(bintot, NBC);
  binsort1<<<nblk, 256, 0, stream>>>(src, dst, tmp, bofs, bintot, NBC, E, REPS);
  binscan<<<1, 512, 0, stream>>>(bintot, binbase, NBC);
  binsort2<<<NBC, 512, 0, stream>>>(tmp, bofs, binbase, csrc, cnt, dis, offs,
                                    NBC, nblk, N, REPS);
  pack_heads_w<<<(128 * 64 + 255) / 256, 256, 0, stream>>>(piW, muW, lsW, W64);

  const int NB8 = (N + 7) / 8;       // agg: 2 nodes/wave, 4 waves/block
  const int NBG = (N + 127) / 128;   // mfma gemm: 128 rows/block

  // ---- layers ----
  gemm128_mfma<false><<<NBG, 256, 0, stream>>>(x, W1, h16, N, REPS);
  agg_kernel<__half><<<NB8, 256, 0, stream>>>(h16, csrc, offs, cnt, dis, b1,
                                              bufB16, N);
  gemm128_mfma<true><<<NBG, 256, 0, stream>>>(bufB16, W2, h16, N, REPS);
  agg_kernel<float><<<NB8, 256, 0, stream>>>(h16, csrc, offs, cnt, dis, b2,
                                             bufB, N);

  // ---- heads (GEMM + softmax fused) ----
  heads_fused<<<(N + 63) / 64, 256, 0, stream>>>(bufB, W64, pib, mub, lsb, out, N,
                                                 REPS);
}

// Round 11
// 615.876 us; speedup vs baseline: 1.4343x; 1.4343x over previous
//
#include <hip/hip_runtime.h>
#include <hip/hip_fp16.h>
#include <cstdint>
#include <cstddef>

#define IN_DIM 128
#define HID    128
#define NG     20
#define T      4096        // edges per binsort1 block
#define MAXB   400         // max coarse bins (N <= 102400)
#define BIN_CAP 12288      // LDS records per bin: mean 8192, sigma~90 -> +45 sigma

typedef _Float16 half8 __attribute__((ext_vector_type(8)));
typedef _Float16 half4 __attribute__((ext_vector_type(4)));
typedef float    f32x4 __attribute__((ext_vector_type(4)));

// ============ level 1: block-local sort into coarse bins (256 nodes/bin) ============
// (bintot atomics removed -- binbase is now recomputed from bofs deltas in gemm1_scan)
__global__ __launch_bounds__(512) void binsort1(const int* __restrict__ src,
    const int* __restrict__ dst, int* __restrict__ tmp, int* __restrict__ bofs,
    int NBC, int E) {
  __shared__ int lhist[MAXB];
  __shared__ int lscan[512];
  __shared__ int lcur[MAXB];
  __shared__ int sbuf[T];
  int tid = threadIdx.x;
  int tile0 = blockIdx.x * T;
  int m = E - tile0; if (m > T) m = T;

  for (int i = tid; i < NBC; i += 512) lhist[i] = 0;
  __syncthreads();

  int dreg[8];
#pragma unroll
  for (int j = 0; j < 8; ++j) {
    int idx = j * 512 + tid;
    dreg[j] = -1;
    if (idx < m) {
      int d = dst[tile0 + idx];
      dreg[j] = d;
      atomicAdd(&lhist[d >> 8], 1);
    }
  }
  __syncthreads();

  int v = (tid < NBC) ? lhist[tid] : 0;
  lscan[tid] = v;
  __syncthreads();
  for (int o = 1; o < 512; o <<= 1) {
    int t = (tid >= o) ? lscan[tid - o] : 0;
    __syncthreads();
    lscan[tid] += t;
    __syncthreads();
  }
  if (tid < NBC) lcur[tid] = lscan[tid] - v;
  __syncthreads();

  int ST = NBC + 1;
  for (int i = tid; i < NBC; i += 512) bofs[(size_t)blockIdx.x * ST + i] = lcur[i];
  if (tid == 0) bofs[(size_t)blockIdx.x * ST + NBC] = m;
  __syncthreads();

#pragma unroll
  for (int j = 0; j < 8; ++j) {
    int idx = j * 512 + tid;
    if (idx < m) {
      int d = dreg[j];
      int s = src[tile0 + idx];
      int slot = atomicAdd(&lcur[d >> 8], 1);
      sbuf[slot] = ((d & 255) << 17) | s;
    }
  }
  __syncthreads();

  int nv = m >> 2;
  int4* out4 = (int4*)(tmp + tile0);
  const int4* sb4 = (const int4*)sbuf;
  for (int i = tid; i < nv; i += 512) out4[i] = sb4[i];
  for (int i = (nv << 2) + tid; i < m; i += 512) tmp[tile0 + i] = sbuf[i];
}

// ============ MFMA GEMM body, f16 out: C16[128,128] tile = A[128,128] @ B[128,128] ====
template<bool F16IN>
__device__ __forceinline__ void gemm_body(const void* __restrict__ Av,
    const float* __restrict__ B, __half* __restrict__ C, int M, int m0,
    char* smemc) {
  _Float16 (*sA)[136] = (_Float16(*)[136])smemc;
  const int tid = threadIdx.x;
  const int wave = tid >> 6, lane = tid & 63;
  const int nbase = wave << 5;
  const int lrow = lane & 15;
  const int khi  = lane >> 4;
  const float* wcol = B + nbase + lrow;

  float bA[2][8], bB[2][8];
#pragma unroll
  for (int nf = 0; nf < 2; ++nf)
#pragma unroll
    for (int rr = 0; rr < 8; ++rr)
      bA[nf][rr] = wcol[(size_t)(khi * 8 + rr) * 128 + nf * 16];

  if constexpr (F16IN) {
    const __half* A = (const __half*)Av;
#pragma unroll
    for (int q = 0; q < 8; ++q) {
      int idx = q * 256 + tid;
      int r = idx >> 4;
      int cc = (idx & 15) << 3;
      half8 hv = {};
      if (m0 + r < M) hv = *(const half8*)(A + (size_t)(m0 + r) * 128 + cc);
      *(half8*)(&sA[r][cc]) = hv;
    }
  } else {
    const float* A = (const float*)Av;
#pragma unroll
    for (int q = 0; q < 16; ++q) {
      int idx = q * 256 + tid;
      int r = idx >> 5;
      int cc = (idx & 31) << 2;
      float4 v = make_float4(0.f, 0.f, 0.f, 0.f);
      if (m0 + r < M) v = *(const float4*)(A + (size_t)(m0 + r) * 128 + cc);
      half4 hv;
      hv[0] = (_Float16)v.x; hv[1] = (_Float16)v.y;
      hv[2] = (_Float16)v.z; hv[3] = (_Float16)v.w;
      *(half4*)(&sA[r][cc]) = hv;
    }
  }
  __syncthreads();

  f32x4 acc[8][2];
#pragma unroll
  for (int mf = 0; mf < 8; ++mf)
#pragma unroll
    for (int nf = 0; nf < 2; ++nf) acc[mf][nf] = (f32x4){0.f, 0.f, 0.f, 0.f};

  auto loadB = [&](float (&dst)[2][8], int ks) {
#pragma unroll
    for (int nf = 0; nf < 2; ++nf)
#pragma unroll
      for (int rr = 0; rr < 8; ++rr)
        dst[nf][rr] = wcol[(size_t)(ks * 32 + khi * 8 + rr) * 128 + nf * 16];
  };
  half8 bf0, bf1;
  auto cvtB = [&](float (&s)[2][8]) {
#pragma unroll
    for (int rr = 0; rr < 8; ++rr) {
      bf0[rr] = (_Float16)s[0][rr];
      bf1[rr] = (_Float16)s[1][rr];
    }
  };
  auto mfmas = [&](int ks) {
#pragma unroll
    for (int mf = 0; mf < 8; ++mf) {
      half8 a = *(const half8*)(&sA[mf * 16 + lrow][khi * 8 + ks * 32]);
      acc[mf][0] = __builtin_amdgcn_mfma_f32_16x16x32_f16(a, bf0, acc[mf][0], 0, 0, 0);
      acc[mf][1] = __builtin_amdgcn_mfma_f32_16x16x32_f16(a, bf1, acc[mf][1], 0, 0, 0);
    }
  };
  cvtB(bA); loadB(bB, 1); mfmas(0);
  cvtB(bB); loadB(bA, 2); mfmas(1);
  cvtB(bA); loadB(bB, 3); mfmas(2);
  cvtB(bB);               mfmas(3);

#pragma unroll
  for (int mf = 0; mf < 8; ++mf) {
    int r0 = mf * 16 + khi * 4;
#pragma unroll
    for (int nf = 0; nf < 2; ++nf) {
      int ccol = nbase + nf * 16 + lrow;
#pragma unroll
      for (int reg = 0; reg < 4; ++reg) {
        int r = m0 + r0 + reg;
        if (r < M) C[(size_t)r * 128 + ccol] = __float2half(acc[mf][nf][reg]);
      }
    }
  }
}

// ============ gemm1 + binscan + pack in one launch (kills 2 kernel boundaries) ========
// Blocks [0, NBG): gemm1 tiles. Block NBG: recompute bintot from bofs deltas,
// scan -> binbase, then pack heads weights. The 1-block scan hides under gemm1.
__global__ __launch_bounds__(256) void gemm1_scan(const float* __restrict__ x,
    const float* __restrict__ W1, __half* __restrict__ h16, int M, int NBG,
    const int* __restrict__ bofs, int* __restrict__ binbase, int NBC, int nblk,
    const float* __restrict__ piW, const float* __restrict__ muW,
    const float* __restrict__ lsW, float* __restrict__ W64) {
  __shared__ char smem[128 * 136 * 2];
  __shared__ int ssc[512];
  int tid = threadIdx.x;
  if (blockIdx.x < (unsigned)NBG) {
    gemm_body<false>(x, W1, h16, M, blockIdx.x * 128, smem);
    return;
  }
  // ---- scan block: bintot[b] = sum_r (bofs[r][b+1]-bofs[r][b]) ----
  int ST = NBC + 1;
  int t0 = 0, t1 = 0;
  int r = 0;
  for (; r + 4 <= nblk; r += 4) {
    const int* r0 = bofs + (size_t)r * ST;
    const int* r1 = r0 + ST;
    const int* r2 = r1 + ST;
    const int* r3 = r2 + ST;
    if (tid < NBC)
      t0 += (r0[tid + 1] - r0[tid]) + (r1[tid + 1] - r1[tid]) +
            (r2[tid + 1] - r2[tid]) + (r3[tid + 1] - r3[tid]);
    if (256 + tid < NBC)
      t1 += (r0[257 + tid] - r0[256 + tid]) + (r1[257 + tid] - r1[256 + tid]) +
            (r2[257 + tid] - r2[256 + tid]) + (r3[257 + tid] - r3[256 + tid]);
  }
  for (; r < nblk; ++r) {
    const int* r0 = bofs + (size_t)r * ST;
    if (tid < NBC)       t0 += r0[tid + 1] - r0[tid];
    if (256 + tid < NBC) t1 += r0[257 + tid] - r0[256 + tid];
  }
  ssc[tid] = t0; ssc[256 + tid] = t1;
  __syncthreads();
  for (int o = 1; o < 512; o <<= 1) {
    int a0 = (tid >= o) ? ssc[tid - o] : 0;
    int a1 = (256 + tid >= o) ? ssc[256 + tid - o] : 0;
    __syncthreads();
    ssc[tid] += a0; ssc[256 + tid] += a1;
    __syncthreads();
  }
  if (tid < NBC)       binbase[tid]       = ssc[tid] - t0;
  if (256 + tid < NBC) binbase[256 + tid] = ssc[256 + tid] - t1;
  // ---- pack heads weights ----
  for (int i = tid; i < 128 * 64; i += 256) {
    int k = i >> 6, j = i & 63;
    float v = 0.f;
    if (j < 20)      v = piW[k * 20 + j];
    else if (j < 40) v = muW[k * 20 + (j - 20)];
    else if (j < 60) v = lsW[k * 20 + (j - 40)];
    W64[i] = v;
  }
}

// ============ level 2 v3: fully LDS-windowed (R10 measured: 5x write amp, 69 us) ======
// One bin (~8.2K records, 33 KB) fits LDS. Single global pass appends records to
// bufA + histogram; scan; LDS->LDS scatter to bufB; coalesced int4 stream-out.
// Kills the 66 MB/dispatch write amplification and the second global tmp pass.
// 96 KB LDS -> 1 block/CU, but grid=391 is grid-limited anyway.
__global__ __launch_bounds__(512) void binsort2(const int* __restrict__ tmp,
    const int* __restrict__ bofs, const int* __restrict__ binbase,
    int* __restrict__ csrc, int* __restrict__ cnt, float* __restrict__ dis,
    int* __restrict__ offs, int NBC, int nblk, int N) {
  __shared__ int bufA[BIN_CAP];
  __shared__ int bufB[BIN_CAP];
  __shared__ int lcnt[256];
  __shared__ int lsc[256];
  __shared__ int lcur[256];
  __shared__ int appendTot;
  int b = blockIdx.x;
  int tid = threadIdx.x;
  if (tid == 0) appendTot = 0;
  if (tid < 256) lcnt[tid] = 0;
  __syncthreads();
  int ST = NBC + 1;

  // pass 1: append + count (single global read of this bin's records)
  for (int r = tid; r < nblk; r += 512) {
    int s  = bofs[(size_t)r * ST + b];
    int e2 = bofs[(size_t)r * ST + b + 1];
    int k = e2 - s;
    if (k > 0) {
      int pos = atomicAdd(&appendTot, k);
      if (pos + k > BIN_CAP) k = (pos < BIN_CAP) ? (BIN_CAP - pos) : 0;  // unreachable: cap = mean+45sigma
      int gb = r * T + s;
      for (int i = 0; i < k; ++i) {
        int rec = tmp[gb + i];
        bufA[pos + i] = rec;
        atomicAdd(&lcnt[(rec >> 17) & 255], 1);
      }
    }
  }
  __syncthreads();
  int total = appendTot; if (total > BIN_CAP) total = BIN_CAP;

  // scan lcnt -> exclusive (256 of 512 threads; all threads hit barriers)
  int v = (tid < 256) ? lcnt[tid] : 0;
  if (tid < 256) lsc[tid] = v;
  __syncthreads();
  for (int o = 1; o < 256; o <<= 1) {
    int t = 0;
    if (tid < 256 && tid >= o) t = lsc[tid - o];
    __syncthreads();
    if (tid < 256) lsc[tid] += t;
    __syncthreads();
  }
  int gbase = binbase[b];
  if (tid < 256) {
    int excl = lsc[tid] - v;
    lcur[tid] = excl;                 // LOCAL offset within bin
    int node = (b << 8) + tid;
    if (node < N) {
      cnt[node] = v;
      dis[node] = rsqrtf((float)v + 1.0f);
      offs[node] = gbase + excl;
    }
  }
  __syncthreads();

  // LDS->LDS scatter (strip node bits; csrc stores plain src)
  for (int i = tid; i < total; i += 512) {
    int rec = bufA[i];
    int pos = atomicAdd(&lcur[(rec >> 17) & 255], 1);
    bufB[pos] = rec & 0x1FFFF;
  }
  __syncthreads();

  // coalesced stream-out: csrc[gbase .. gbase+total)
  int head = (4 - (gbase & 3)) & 3; if (head > total) head = total;
  for (int i = tid; i < head; i += 512) csrc[gbase + i] = bufB[i];
  int rem = total - head;
  int nv = rem >> 2;
  int4* dst4 = (int4*)(csrc + gbase + head);
  for (int i = tid; i < nv; i += 512) {
    int j = head + i * 4;
    dst4[i] = make_int4(bufB[j], bufB[j + 1], bufB[j + 2], bufB[j + 3]);
  }
  for (int i = head + (nv << 2) + tid; i < total; i += 512)
    csrc[gbase + i] = bufB[i];
}

// standalone gemm (layer 2, f16 input)
__global__ __launch_bounds__(256) void gemm128_mfma_f16(const __half* __restrict__ A,
    const float* __restrict__ B, __half* __restrict__ C, int M) {
  __shared__ char smem[128 * 136 * 2];
  gemm_body<true>(A, B, C, M, blockIdx.x * 128, smem);
}

// ============ aggregation: two nodes per wave, interleaved gather chains ============
// PROVEN (115 us @ 3.75 TB/s pattern roofline -- 3 falsifications: 2x concurrency
// flat (R2), barrier-phasing -2.2x (R3), channel-chunking -3.2x (R5)). OutT=__half
// for layer 1 (rounding point identical; write traffic halves).
template<typename OutT>
__global__ __launch_bounds__(256) void agg_kernel(const __half* __restrict__ h,
    const int* __restrict__ csrc,
    const int* __restrict__ offs, const int* __restrict__ cnt,
    const float* __restrict__ dis, const float* __restrict__ bias,
    OutT* __restrict__ out, int n) {
  int wave = threadIdx.x >> 6;
  int lane = threadIdx.x & 63;
  int i0 = (blockIdx.x * 4 + wave) * 2;
  if (i0 >= n) return;
  int i1 = i0 + 1;
  bool has1 = i1 < n;
  int c = lane * 2;

  int st0 = offs[i0];
  int m0  = cnt[i0];
  float d0 = dis[i0];
  int st1 = 0, m1 = 0;
  float d1 = 0.f;
  if (has1) { st1 = offs[i1]; m1 = cnt[i1]; d1 = dis[i1]; }

  float ax0 = 0.f, ay0 = 0.f, ax1 = 0.f, ay1 = 0.f;
  int mMax = m0 > m1 ? m0 : m1;

  for (int base = 0; base < mMax; base += 64) {
    int mcA = m0 - base; mcA = mcA < 0 ? 0 : (mcA > 64 ? 64 : mcA);
    int mcB = m1 - base; mcB = mcB < 0 ? 0 : (mcB > 64 ? 64 : mcB);
    int mc = mcA > mcB ? mcA : mcB;

    int sA = 0, sB = 0;
    float wA = 0.f, wB = 0.f;
    if (lane < mcA) sA = csrc[st0 + base + lane];
    if (lane < mcB) sB = csrc[st1 + base + lane];
    if (lane < mcA) wA = dis[sA] * d0;
    if (lane < mcB) wB = dis[sB] * d1;

    int j = 0;
    for (; j + 4 <= mc; j += 4) {
      int   a0 = __shfl(sA, j);
      int   a1 = __shfl(sA, j + 1);
      int   a2 = __shfl(sA, j + 2);
      int   a3 = __shfl(sA, j + 3);
      int   b0 = __shfl(sB, j);
      int   b1 = __shfl(sB, j + 1);
      int   b2 = __shfl(sB, j + 2);
      int   b3 = __shfl(sB, j + 3);
      float u0 = __shfl(wA, j);
      float u1 = __shfl(wA, j + 1);
      float u2 = __shfl(wA, j + 2);
      float u3 = __shfl(wA, j + 3);
      float v0 = __shfl(wB, j);
      float v1 = __shfl(wB, j + 1);
      float v2 = __shfl(wB, j + 2);
      float v3 = __shfl(wB, j + 3);
      float2 hA0 = __half22float2(*(const __half2*)(h + ((size_t)a0 << 7) + c));
      float2 hA1 = __half22float2(*(const __half2*)(h + ((size_t)a1 << 7) + c));
      float2 hA2 = __half22float2(*(const __half2*)(h + ((size_t)a2 << 7) + c));
      float2 hA3 = __half22float2(*(const __half2*)(h + ((size_t)a3 << 7) + c));
      float2 hB0 = __half22float2(*(const __half2*)(h + ((size_t)b0 << 7) + c));
      float2 hB1 = __half22float2(*(const __half2*)(h + ((size_t)b1 << 7) + c));
      float2 hB2 = __half22float2(*(const __half2*)(h + ((size_t)b2 << 7) + c));
      float2 hB3 = __half22float2(*(const __half2*)(h + ((size_t)b3 << 7) + c));
      ax0 = fmaf(hA0.x, u0, ax0); ay0 = fmaf(hA0.y, u0, ay0);
      ax0 = fmaf(hA1.x, u1, ax0); ay0 = fmaf(hA1.y, u1, ay0);
      ax0 = fmaf(hA2.x, u2, ax0); ay0 = fmaf(hA2.y, u2, ay0);
      ax0 = fmaf(hA3.x, u3, ax0); ay0 = fmaf(hA3.y, u3, ay0);
      ax1 = fmaf(hB0.x, v0, ax1); ay1 = fmaf(hB0.y, v0, ay1);
      ax1 = fmaf(hB1.x, v1, ax1); ay1 = fmaf(hB1.y, v1, ay1);
      ax1 = fmaf(hB2.x, v2, ax1); ay1 = fmaf(hB2.y, v2, ay1);
      ax1 = fmaf(hB3.x, v3, ax1); ay1 = fmaf(hB3.y, v3, ay1);
    }
    for (; j < mc; ++j) {
      int   a0 = __shfl(sA, j);
      int   b0 = __shfl(sB, j);
      float u0 = __shfl(wA, j);
      float v0 = __shfl(wB, j);
      float2 hA0 = __half22float2(*(const __half2*)(h + ((size_t)a0 << 7) + c));
      float2 hB0 = __half22float2(*(const __half2*)(h + ((size_t)b0 << 7) + c));
      ax0 = fmaf(hA0.x, u0, ax0); ay0 = fmaf(hA0.y, u0, ay0);
      ax1 = fmaf(hB0.x, v0, ax1); ay1 = fmaf(hB0.y, v0, ay1);
    }
  }

  float2 bv = *(const float2*)(bias + c);
  {
    float dd = d0 * d0;
    float2 hs = __half22float2(*(const __half2*)(h + ((size_t)i0 << 7) + c));
    float vx = fmaxf(fmaf(hs.x, dd, ax0) + bv.x, 0.f);
    float vy = fmaxf(fmaf(hs.y, dd, ay0) + bv.y, 0.f);
    if constexpr (sizeof(OutT) == 2) {
      *(__half2*)((__half*)out + (size_t)i0 * 128 + c) = __floats2half2_rn(vx, vy);
    } else {
      *(float2*)((float*)out + (size_t)i0 * 128 + c) = make_float2(vx, vy);
    }
  }
  if (has1) {
    float dd = d1 * d1;
    float2 hs = __half22float2(*(const __half2*)(h + ((size_t)i1 << 7) + c));
    float vx = fmaxf(fmaf(hs.x, dd, ax1) + bv.x, 0.f);
    float vy = fmaxf(fmaf(hs.y, dd, ay1) + bv.y, 0.f);
    if constexpr (sizeof(OutT) == 2) {
      *(__half2*)((__half*)out + (size_t)i1 * 128 + c) = __floats2half2_rn(vx, vy);
    } else {
      *(float2*)((float*)out + (size_t)i1 * 128 + c) = make_float2(vx, vy);
    }
  }
}

// ============ fused heads: GEMM [M,128]@[128,64] + bias + softmax(20) + scatter ====
#define KC 64
__global__ __launch_bounds__(256) void heads_fused(const float* __restrict__ A,
    const float* __restrict__ B, const float* __restrict__ pib,
    const float* __restrict__ mub, const float* __restrict__ lsb,
    float* __restrict__ out, int n) {
  __shared__ float sA[64][KC + 4];
  __shared__ float sB[KC][68];
  __shared__ float sOut[64][68];
  int tid = threadIdx.x;
  int m0 = blockIdx.x * 64;
  int tr = tid >> 4;   // 0..15
  int tc = tid & 15;   // 0..15
  float acc[4][4];
#pragma unroll
  for (int i = 0; i < 4; ++i)
#pragma unroll
    for (int j = 0; j < 4; ++j) acc[i][j] = 0.f;

  for (int k0 = 0; k0 < 128; k0 += KC) {
#pragma unroll
    for (int q = 0; q < 4; ++q) {
      int idx = q * 256 + tid;
      int r = idx >> 4;
      int kk = (idx & 15) << 2;
      float4 v = make_float4(0.f, 0.f, 0.f, 0.f);
      if (m0 + r < n) v = *(const float4*)(A + (size_t)(m0 + r) * 128 + k0 + kk);
      *(float4*)(&sA[r][kk]) = v;
    }
#pragma unroll
    for (int q = 0; q < 4; ++q) {
      int idx = q * 256 + tid;
      int kk = idx >> 4;
      int nn = (idx & 15) << 2;
      *(float4*)(&sB[kk][nn]) = *(const float4*)(B + (size_t)(k0 + kk) * 64 + nn);
    }
    __syncthreads();
#pragma unroll 4
    for (int k = 0; k < KC; k += 4) {
      float4 a0 = *(const float4*)(&sA[tr][k]);
      float4 a1 = *(const float4*)(&sA[tr + 16][k]);
      float4 a2 = *(const float4*)(&sA[tr + 32][k]);
      float4 a3 = *(const float4*)(&sA[tr + 48][k]);
#pragma unroll
      for (int u = 0; u < 4; ++u) {
        float4 b = *(const float4*)(&sB[k + u][tc * 4]);
        float av[4] = {((const float*)&a0)[u], ((const float*)&a1)[u],
                       ((const float*)&a2)[u], ((const float*)&a3)[u]};
#pragma unroll
        for (int i = 0; i < 4; ++i) {
          acc[i][0] = fmaf(av[i], b.x, acc[i][0]);
          acc[i][1] = fmaf(av[i], b.y, acc[i][1]);
          acc[i][2] = fmaf(av[i], b.z, acc[i][2]);
          acc[i][3] = fmaf(av[i], b.w, acc[i][3]);
        }
      }
    }
    __syncthreads();
  }

#pragma unroll
  for (int i = 0; i < 4; ++i)
#pragma unroll
    for (int j = 0; j < 4; ++j) sOut[tr + 16 * i][tc * 4 + j] = acc[i][j];
  __syncthreads();

  int wave = tid >> 6, lane = tid & 63;
  size_t nb = (size_t)n * NG;
  for (int t = 0; t < 16; ++t) {
    int rr = wave * 16 + t;
    int node = m0 + rr;
    if (node >= n) break;   // wave-uniform
    float v = 0.f;
    if (lane < 60) {
      v = sOut[rr][lane];
      v += (lane < 20) ? pib[lane] : (lane < 40) ? mub[lane - 20] : lsb[lane - 40];
    }
    float pv = (lane < 20) ? v : -__builtin_inff();
    float mx = pv;
    for (int o = 16; o > 0; o >>= 1) mx = fmaxf(mx, __shfl_down(mx, o, 32));
    mx = __shfl(mx, 0, 32);
    float ev = (lane < 20) ? expf(v - mx) : 0.f;
    float sm = ev;
    for (int o = 16; o > 0; o >>= 1) sm += __shfl_down(sm, o, 32);
    sm = __shfl(sm, 0, 32);
    if (lane < 20)      out[(size_t)node * NG + lane] = ev / sm;
    else if (lane < 40) out[nb + (size_t)node * NG + (lane - 20)] = v;
    else if (lane < 60) out[2 * nb + (size_t)node * NG + (lane - 40)] = v;
  }
}

extern "C" void kernel_launch(void* const* d_in, const int* in_sizes, int n_in,
                              void* d_out, int out_size, void* d_ws, size_t ws_size,
                              hipStream_t stream) {
  const float* x   = (const float*)d_in[0];
  const int*   ei  = (const int*)d_in[1];
  const float* W1  = (const float*)d_in[2];
  const float* b1  = (const float*)d_in[3];
  const float* W2  = (const float*)d_in[4];
  const float* b2  = (const float*)d_in[5];
  const float* piW = (const float*)d_in[6];
  const float* pib = (const float*)d_in[7];
  const float* muW = (const float*)d_in[8];
  const float* mub = (const float*)d_in[9];
  const float* lsW = (const float*)d_in[10];
  const float* lsb = (const float*)d_in[11];
  float* out = (float*)d_out;

  const int N = in_sizes[0] / IN_DIM;
  const int E = in_sizes[1] / 2;
  const int* src = ei;
  const int* dst = ei + E;

  const int NBC  = (N + 255) >> 8;          // 391 coarse bins
  const int nblk = (E + T - 1) / T;         // 782 level-1 blocks
  const int ST   = NBC + 1;

  // workspace layout
  char* p = (char*)d_ws;
  char* regionH = p;                        p += (size_t)N * HID * sizeof(__half);
  __half* h16  = (__half*)regionH;
  char* regionR = p;                        // tmp -> bufB16 -> bufB (sequential reuse)
  size_t szR = (size_t)N * HID * sizeof(float);
  size_t szT = (size_t)E * sizeof(int);
  p += (szR > szT ? szR : szT);
  int*    tmp    = (int*)regionR;
  __half* bufB16 = (__half*)regionR;
  float*  bufB   = (float*)regionR;
  int*   csrc   = (int*)p;                  p += (size_t)E * sizeof(int);
  int*   bofs   = (int*)p;                  p += (size_t)nblk * ST * sizeof(int);
  int*   binbase= (int*)p;                  p += (size_t)MAXB * sizeof(int);
  int*   cnt    = (int*)p;                  p += (size_t)N * sizeof(int);
  int*   offs   = (int*)p;                  p += (size_t)N * sizeof(int);
  float* dis    = (float*)p;                p += (size_t)N * sizeof(float);
  float* W64    = (float*)p;                p += (size_t)128 * 64 * sizeof(float);

  const int NB8 = (N + 7) / 8;       // agg: 2 nodes/wave, 4 waves/block
  const int NBG = (N + 127) / 128;   // mfma gemm: 128 rows/block

  // ---- 7 launches total (was 10) ----
  binsort1<<<nblk, 512, 0, stream>>>(src, dst, tmp, bofs, NBC, E);
  gemm1_scan<<<NBG + 1, 256, 0, stream>>>(x, W1, h16, N, NBG, bofs, binbase,
                                          NBC, nblk, piW, muW, lsW, W64);
  binsort2<<<NBC, 512, 0, stream>>>(tmp, bofs, binbase, csrc, cnt, dis, offs,
                                    NBC, nblk, N);
  agg_kernel<__half><<<NB8, 256, 0, stream>>>(h16, csrc, offs, cnt, dis, b1,
                                              bufB16, N);
  gemm128_mfma_f16<<<NBG, 256, 0, stream>>>(bufB16, W2, h16, N);
  agg_kernel<float><<<NB8, 256, 0, stream>>>(h16, csrc, offs, cnt, dis, b2,
                                             bufB, N);
  heads_fused<<<(N + 63) / 64, 256, 0, stream>>>(bufB, W64, pib, mub, lsb, out, N);
}

// Round 13
// 505.482 us; speedup vs baseline: 1.7475x; 1.2184x over previous
//
#include <hip/hip_runtime.h>
#include <hip/hip_fp16.h>
#include <cstdint>
#include <cstddef>

#define IN_DIM 128
#define HID    128
#define NG     20
#define T      4096        // edges per binsort1 block
#define MAXB   400         // max coarse bins (N <= 102400)
#define BIN_CAP 12288      // LDS records per bin: mean 8192, sigma~90 -> +45 sigma

typedef _Float16 half8 __attribute__((ext_vector_type(8)));
typedef _Float16 half4 __attribute__((ext_vector_type(4)));
typedef float    f32x4 __attribute__((ext_vector_type(4)));

__global__ void zero_ints(int* __restrict__ a, int n) {
  int i = blockIdx.x * blockDim.x + threadIdx.x;
  if (i < n) a[i] = 0;
}

// ============ level 1: block-local sort into coarse bins (256 nodes/bin) ============
// bintot accumulated DISTRIBUTED (per-block atomics, L2-resident) -- R11 lesson:
// recomputing it serially in one block cost 178 us.
__global__ __launch_bounds__(512) void binsort1(const int* __restrict__ src,
    const int* __restrict__ dst, int* __restrict__ tmp, int* __restrict__ bofs,
    int* __restrict__ bintot, int NBC, int E) {
  __shared__ int lhist[MAXB];
  __shared__ int lscan[512];
  __shared__ int lcur[MAXB];
  __shared__ int sbuf[T];
  int tid = threadIdx.x;
  int tile0 = blockIdx.x * T;
  int m = E - tile0; if (m > T) m = T;

  for (int i = tid; i < NBC; i += 512) lhist[i] = 0;
  __syncthreads();

  int dreg[8];
#pragma unroll
  for (int j = 0; j < 8; ++j) {
    int idx = j * 512 + tid;
    dreg[j] = -1;
    if (idx < m) {
      int d = dst[tile0 + idx];
      dreg[j] = d;
      atomicAdd(&lhist[d >> 8], 1);
    }
  }
  __syncthreads();

  int v = (tid < NBC) ? lhist[tid] : 0;
  lscan[tid] = v;
  __syncthreads();
  for (int o = 1; o < 512; o <<= 1) {
    int t = (tid >= o) ? lscan[tid - o] : 0;
    __syncthreads();
    lscan[tid] += t;
    __syncthreads();
  }
  if (tid < NBC) lcur[tid] = lscan[tid] - v;
  __syncthreads();

  int ST = NBC + 1;
  for (int i = tid; i < NBC; i += 512) bofs[(size_t)blockIdx.x * ST + i] = lcur[i];
  if (tid == 0) bofs[(size_t)blockIdx.x * ST + NBC] = m;
  for (int i = tid; i < NBC; i += 512)
    if (lhist[i]) atomicAdd(&bintot[i], lhist[i]);
  __syncthreads();

#pragma unroll
  for (int j = 0; j < 8; ++j) {
    int idx = j * 512 + tid;
    if (idx < m) {
      int d = dreg[j];
      int s = src[tile0 + idx];
      int slot = atomicAdd(&lcur[d >> 8], 1);
      sbuf[slot] = ((d & 255) << 17) | s;
    }
  }
  __syncthreads();

  int nv = m >> 2;
  int4* out4 = (int4*)(tmp + tile0);
  const int4* sb4 = (const int4*)sbuf;
  for (int i = tid; i < nv; i += 512) out4[i] = sb4[i];
  for (int i = (nv << 2) + tid; i < m; i += 512) tmp[tile0 + i] = sbuf[i];
}

// ============ MFMA GEMM body, f16 out: C16[128,128] tile = A[128,128] @ B[128,128] ====
template<bool F16IN>
__device__ __forceinline__ void gemm_body(const void* __restrict__ Av,
    const float* __restrict__ B, __half* __restrict__ C, int M, int m0,
    char* smemc) {
  _Float16 (*sA)[136] = (_Float16(*)[136])smemc;
  const int tid = threadIdx.x;
  const int wave = tid >> 6, lane = tid & 63;
  const int nbase = wave << 5;
  const int lrow = lane & 15;
  const int khi  = lane >> 4;
  const float* wcol = B + nbase + lrow;

  float bA[2][8], bB[2][8];
#pragma unroll
  for (int nf = 0; nf < 2; ++nf)
#pragma unroll
    for (int rr = 0; rr < 8; ++rr)
      bA[nf][rr] = wcol[(size_t)(khi * 8 + rr) * 128 + nf * 16];

  if constexpr (F16IN) {
    const __half* A = (const __half*)Av;
#pragma unroll
    for (int q = 0; q < 8; ++q) {
      int idx = q * 256 + tid;
      int r = idx >> 4;
      int cc = (idx & 15) << 3;
      half8 hv = {};
      if (m0 + r < M) hv = *(const half8*)(A + (size_t)(m0 + r) * 128 + cc);
      *(half8*)(&sA[r][cc]) = hv;
    }
  } else {
    const float* A = (const float*)Av;
#pragma unroll
    for (int q = 0; q < 16; ++q) {
      int idx = q * 256 + tid;
      int r = idx >> 5;
      int cc = (idx & 31) << 2;
      float4 v = make_float4(0.f, 0.f, 0.f, 0.f);
      if (m0 + r < M) v = *(const float4*)(A + (size_t)(m0 + r) * 128 + cc);
      half4 hv;
      hv[0] = (_Float16)v.x; hv[1] = (_Float16)v.y;
      hv[2] = (_Float16)v.z; hv[3] = (_Float16)v.w;
      *(half4*)(&sA[r][cc]) = hv;
    }
  }
  __syncthreads();

  f32x4 acc[8][2];
#pragma unroll
  for (int mf = 0; mf < 8; ++mf)
#pragma unroll
    for (int nf = 0; nf < 2; ++nf) acc[mf][nf] = (f32x4){0.f, 0.f, 0.f, 0.f};

  auto loadB = [&](float (&dst)[2][8], int ks) {
#pragma unroll
    for (int nf = 0; nf < 2; ++nf)
#pragma unroll
      for (int rr = 0; rr < 8; ++rr)
        dst[nf][rr] = wcol[(size_t)(ks * 32 + khi * 8 + rr) * 128 + nf * 16];
  };
  half8 bf0, bf1;
  auto cvtB = [&](float (&s)[2][8]) {
#pragma unroll
    for (int rr = 0; rr < 8; ++rr) {
      bf0[rr] = (_Float16)s[0][rr];
      bf1[rr] = (_Float16)s[1][rr];
    }
  };
  auto mfmas = [&](int ks) {
#pragma unroll
    for (int mf = 0; mf < 8; ++mf) {
      half8 a = *(const half8*)(&sA[mf * 16 + lrow][khi * 8 + ks * 32]);
      acc[mf][0] = __builtin_amdgcn_mfma_f32_16x16x32_f16(a, bf0, acc[mf][0], 0, 0, 0);
      acc[mf][1] = __builtin_amdgcn_mfma_f32_16x16x32_f16(a, bf1, acc[mf][1], 0, 0, 0);
    }
  };
  cvtB(bA); loadB(bB, 1); mfmas(0);
  cvtB(bB); loadB(bA, 2); mfmas(1);
  cvtB(bA); loadB(bB, 3); mfmas(2);
  cvtB(bB);               mfmas(3);

#pragma unroll
  for (int mf = 0; mf < 8; ++mf) {
    int r0 = mf * 16 + khi * 4;
#pragma unroll
    for (int nf = 0; nf < 2; ++nf) {
      int ccol = nbase + nf * 16 + lrow;
#pragma unroll
      for (int reg = 0; reg < 4; ++reg) {
        int r = m0 + r0 + reg;
        if (r < M) C[(size_t)r * 128 + ccol] = __float2half(acc[mf][nf][reg]);
      }
    }
  }
}

// ============ gemm1 + tiny binscan + pack in one launch ============
// Extra block only scans the 391-entry bintot (distributed-accumulated in
// binsort1) + packs W64: ~3 us, fully hidden under the 782 gemm tiles.
// (R11 lesson: do NOT recompute bintot serially here -- that was 178 us.)
__global__ __launch_bounds__(256) void gemm1_scan(const float* __restrict__ x,
    const float* __restrict__ W1, __half* __restrict__ h16, int M, int NBG,
    const int* __restrict__ bintot, int* __restrict__ binbase, int NBC,
    const float* __restrict__ piW, const float* __restrict__ muW,
    const float* __restrict__ lsW, float* __restrict__ W64) {
  __shared__ char smem[128 * 136 * 2];
  int tid = threadIdx.x;
  if (blockIdx.x < (unsigned)NBG) {
    gemm_body<false>(x, W1, h16, M, blockIdx.x * 128, smem);
    return;
  }
  // ---- scan block: 512-wide Hillis-Steele with 256 threads ----
  int* ssc = (int*)smem;
  int v0 = (tid < NBC) ? bintot[tid] : 0;
  int v1 = (256 + tid < NBC) ? bintot[256 + tid] : 0;
  ssc[tid] = v0; ssc[256 + tid] = v1;
  __syncthreads();
  for (int o = 1; o < 512; o <<= 1) {
    int a0 = (tid >= o) ? ssc[tid - o] : 0;
    int a1 = (256 + tid >= o) ? ssc[256 + tid - o] : 0;
    __syncthreads();
    ssc[tid] += a0; ssc[256 + tid] += a1;
    __syncthreads();
  }
  if (tid < NBC)       binbase[tid]       = ssc[tid] - v0;
  if (256 + tid < NBC) binbase[256 + tid] = ssc[256 + tid] - v1;
  // ---- pack heads weights ----
  for (int i = tid; i < 128 * 64; i += 256) {
    int k = i >> 6, j = i & 63;
    float v = 0.f;
    if (j < 20)      v = piW[k * 20 + j];
    else if (j < 40) v = muW[k * 20 + (j - 20)];
    else if (j < 60) v = lsW[k * 20 + (j - 40)];
    W64[i] = v;
  }
}

// ============ level 2 v3: fully LDS-windowed (verified R11; kills 5x write amp) ======
__global__ __launch_bounds__(512) void binsort2(const int* __restrict__ tmp,
    const int* __restrict__ bofs, const int* __restrict__ binbase,
    int* __restrict__ csrc, int* __restrict__ cnt, float* __restrict__ dis,
    int* __restrict__ offs, int NBC, int nblk, int N) {
  __shared__ int bufA[BIN_CAP];
  __shared__ int bufB[BIN_CAP];
  __shared__ int lcnt[256];
  __shared__ int lsc[256];
  __shared__ int lcur[256];
  __shared__ int appendTot;
  int b = blockIdx.x;
  int tid = threadIdx.x;
  if (tid == 0) appendTot = 0;
  if (tid < 256) lcnt[tid] = 0;
  __syncthreads();
  int ST = NBC + 1;

  // pass 1: append + count (single global read of this bin's records)
  for (int r = tid; r < nblk; r += 512) {
    int s  = bofs[(size_t)r * ST + b];
    int e2 = bofs[(size_t)r * ST + b + 1];
    int k = e2 - s;
    if (k > 0) {
      int pos = atomicAdd(&appendTot, k);
      if (pos + k > BIN_CAP) k = (pos < BIN_CAP) ? (BIN_CAP - pos) : 0;  // unreachable: cap = mean+45sigma
      int gb = r * T + s;
      for (int i = 0; i < k; ++i) {
        int rec = tmp[gb + i];
        bufA[pos + i] = rec;
        atomicAdd(&lcnt[(rec >> 17) & 255], 1);
      }
    }
  }
  __syncthreads();
  int total = appendTot; if (total > BIN_CAP) total = BIN_CAP;

  // scan lcnt -> exclusive (256 of 512 threads; all threads hit barriers)
  int v = (tid < 256) ? lcnt[tid] : 0;
  if (tid < 256) lsc[tid] = v;
  __syncthreads();
  for (int o = 1; o < 256; o <<= 1) {
    int t = 0;
    if (tid < 256 && tid >= o) t = lsc[tid - o];
    __syncthreads();
    if (tid < 256) lsc[tid] += t;
    __syncthreads();
  }
  int gbase = binbase[b];
  if (tid < 256) {
    int excl = lsc[tid] - v;
    lcur[tid] = excl;                 // LOCAL offset within bin
    int node = (b << 8) + tid;
    if (node < N) {
      cnt[node] = v;
      dis[node] = rsqrtf((float)v + 1.0f);
      offs[node] = gbase + excl;
    }
  }
  __syncthreads();

  // LDS->LDS scatter (strip node bits; csrc stores plain src)
  for (int i = tid; i < total; i += 512) {
    int rec = bufA[i];
    int pos = atomicAdd(&lcur[(rec >> 17) & 255], 1);
    bufB[pos] = rec & 0x1FFFF;
  }
  __syncthreads();

  // coalesced stream-out: csrc[gbase .. gbase+total)
  int head = (4 - (gbase & 3)) & 3; if (head > total) head = total;
  for (int i = tid; i < head; i += 512) csrc[gbase + i] = bufB[i];
  int rem = total - head;
  int nv = rem >> 2;
  int4* dst4 = (int4*)(csrc + gbase + head);
  for (int i = tid; i < nv; i += 512) {
    int j = head + i * 4;
    dst4[i] = make_int4(bufB[j], bufB[j + 1], bufB[j + 2], bufB[j + 3]);
  }
  for (int i = head + (nv << 2) + tid; i < total; i += 512)
    csrc[gbase + i] = bufB[i];
}

// standalone gemm (layer 2, f16 input)
__global__ __launch_bounds__(256) void gemm128_mfma_f16(const __half* __restrict__ A,
    const float* __restrict__ B, __half* __restrict__ C, int M) {
  __shared__ char smem[128 * 136 * 2];
  gemm_body<true>(A, B, C, M, blockIdx.x * 128, smem);
}

// ============ aggregation: two nodes per wave, interleaved gather chains ============
// PROVEN (115 us @ 3.75 TB/s pattern roofline -- 3 falsifications: 2x concurrency
// flat (R2), barrier-phasing -2.2x (R3), channel-chunking -3.2x (R5)). OutT=__half
// for layer 1 (rounding point identical; write traffic halves).
template<typename OutT>
__global__ __launch_bounds__(256) void agg_kernel(const __half* __restrict__ h,
    const int* __restrict__ csrc,
    const int* __restrict__ offs, const int* __restrict__ cnt,
    const float* __restrict__ dis, const float* __restrict__ bias,
    OutT* __restrict__ out, int n) {
  int wave = threadIdx.x >> 6;
  int lane = threadIdx.x & 63;
  int i0 = (blockIdx.x * 4 + wave) * 2;
  if (i0 >= n) return;
  int i1 = i0 + 1;
  bool has1 = i1 < n;
  int c = lane * 2;

  int st0 = offs[i0];
  int m0  = cnt[i0];
  float d0 = dis[i0];
  int st1 = 0, m1 = 0;
  float d1 = 0.f;
  if (has1) { st1 = offs[i1]; m1 = cnt[i1]; d1 = dis[i1]; }

  float ax0 = 0.f, ay0 = 0.f, ax1 = 0.f, ay1 = 0.f;
  int mMax = m0 > m1 ? m0 : m1;

  for (int base = 0; base < mMax; base += 64) {
    int mcA = m0 - base; mcA = mcA < 0 ? 0 : (mcA > 64 ? 64 : mcA);
    int mcB = m1 - base; mcB = mcB < 0 ? 0 : (mcB > 64 ? 64 : mcB);
    int mc = mcA > mcB ? mcA : mcB;

    int sA = 0, sB = 0;
    float wA = 0.f, wB = 0.f;
    if (lane < mcA) sA = csrc[st0 + base + lane];
    if (lane < mcB) sB = csrc[st1 + base + lane];
    if (lane < mcA) wA = dis[sA] * d0;
    if (lane < mcB) wB = dis[sB] * d1;

    int j = 0;
    for (; j + 4 <= mc; j += 4) {
      int   a0 = __shfl(sA, j);
      int   a1 = __shfl(sA, j + 1);
      int   a2 = __shfl(sA, j + 2);
      int   a3 = __shfl(sA, j + 3);
      int   b0 = __shfl(sB, j);
      int   b1 = __shfl(sB, j + 1);
      int   b2 = __shfl(sB, j + 2);
      int   b3 = __shfl(sB, j + 3);
      float u0 = __shfl(wA, j);
      float u1 = __shfl(wA, j + 1);
      float u2 = __shfl(wA, j + 2);
      float u3 = __shfl(wA, j + 3);
      float v0 = __shfl(wB, j);
      float v1 = __shfl(wB, j + 1);
      float v2 = __shfl(wB, j + 2);
      float v3 = __shfl(wB, j + 3);
      float2 hA0 = __half22float2(*(const __half2*)(h + ((size_t)a0 << 7) + c));
      float2 hA1 = __half22float2(*(const __half2*)(h + ((size_t)a1 << 7) + c));
      float2 hA2 = __half22float2(*(const __half2*)(h + ((size_t)a2 << 7) + c));
      float2 hA3 = __half22float2(*(const __half2*)(h + ((size_t)a3 << 7) + c));
      float2 hB0 = __half22float2(*(const __half2*)(h + ((size_t)b0 << 7) + c));
      float2 hB1 = __half22float2(*(const __half2*)(h + ((size_t)b1 << 7) + c));
      float2 hB2 = __half22float2(*(const __half2*)(h + ((size_t)b2 << 7) + c));
      float2 hB3 = __half22float2(*(const __half2*)(h + ((size_t)b3 << 7) + c));
      ax0 = fmaf(hA0.x, u0, ax0); ay0 = fmaf(hA0.y, u0, ay0);
      ax0 = fmaf(hA1.x, u1, ax0); ay0 = fmaf(hA1.y, u1, ay0);
      ax0 = fmaf(hA2.x, u2, ax0); ay0 = fmaf(hA2.y, u2, ay0);
      ax0 = fmaf(hA3.x, u3, ax0); ay0 = fmaf(hA3.y, u3, ay0);
      ax1 = fmaf(hB0.x, v0, ax1); ay1 = fmaf(hB0.y, v0, ay1);
      ax1 = fmaf(hB1.x, v1, ax1); ay1 = fmaf(hB1.y, v1, ay1);
      ax1 = fmaf(hB2.x, v2, ax1); ay1 = fmaf(hB2.y, v2, ay1);
      ax1 = fmaf(hB3.x, v3, ax1); ay1 = fmaf(hB3.y, v3, ay1);
    }
    for (; j < mc; ++j) {
      int   a0 = __shfl(sA, j);
      int   b0 = __shfl(sB, j);
      float u0 = __shfl(wA, j);
      float v0 = __shfl(wB, j);
      float2 hA0 = __half22float2(*(const __half2*)(h + ((size_t)a0 << 7) + c));
      float2 hB0 = __half22float2(*(const __half2*)(h + ((size_t)b0 << 7) + c));
      ax0 = fmaf(hA0.x, u0, ax0); ay0 = fmaf(hA0.y, u0, ay0);
      ax1 = fmaf(hB0.x, v0, ax1); ay1 = fmaf(hB0.y, v0, ay1);
    }
  }

  float2 bv = *(const float2*)(bias + c);
  {
    float dd = d0 * d0;
    float2 hs = __half22float2(*(const __half2*)(h + ((size_t)i0 << 7) + c));
    float vx = fmaxf(fmaf(hs.x, dd, ax0) + bv.x, 0.f);
    float vy = fmaxf(fmaf(hs.y, dd, ay0) + bv.y, 0.f);
    if constexpr (sizeof(OutT) == 2) {
      *(__half2*)((__half*)out + (size_t)i0 * 128 + c) = __floats2half2_rn(vx, vy);
    } else {
      *(float2*)((float*)out + (size_t)i0 * 128 + c) = make_float2(vx, vy);
    }
  }
  if (has1) {
    float dd = d1 * d1;
    float2 hs = __half22float2(*(const __half2*)(h + ((size_t)i1 << 7) + c));
    float vx = fmaxf(fmaf(hs.x, dd, ax1) + bv.x, 0.f);
    float vy = fmaxf(fmaf(hs.y, dd, ay1) + bv.y, 0.f);
    if constexpr (sizeof(OutT) == 2) {
      *(__half2*)((__half*)out + (size_t)i1 * 128 + c) = __floats2half2_rn(vx, vy);
    } else {
      *(float2*)((float*)out + (size_t)i1 * 128 + c) = make_float2(vx, vy);
    }
  }
}

// ============ fused heads: GEMM [M,128]@[128,64] + bias + softmax(20) + scatter ====
#define KC 64
__global__ __launch_bounds__(256) void heads_fused(const float* __restrict__ A,
    const float* __restrict__ B, const float* __restrict__ pib,
    const float* __restrict__ mub, const float* __restrict__ lsb,
    float* __restrict__ out, int n) {
  __shared__ float sA[64][KC + 4];
  __shared__ float sB[KC][68];
  __shared__ float sOut[64][68];
  int tid = threadIdx.x;
  int m0 = blockIdx.x * 64;
  int tr = tid >> 4;   // 0..15
  int tc = tid & 15;   // 0..15
  float acc[4][4];
#pragma unroll
  for (int i = 0; i < 4; ++i)
#pragma unroll
    for (int j = 0; j < 4; ++j) acc[i][j] = 0.f;

  for (int k0 = 0; k0 < 128; k0 += KC) {
#pragma unroll
    for (int q = 0; q < 4; ++q) {
      int idx = q * 256 + tid;
      int r = idx >> 4;
      int kk = (idx & 15) << 2;
      float4 v = make_float4(0.f, 0.f, 0.f, 0.f);
      if (m0 + r < n) v = *(const float4*)(A + (size_t)(m0 + r) * 128 + k0 + kk);
      *(float4*)(&sA[r][kk]) = v;
    }
#pragma unroll
    for (int q = 0; q < 4; ++q) {
      int idx = q * 256 + tid;
      int kk = idx >> 4;
      int nn = (idx & 15) << 2;
      *(float4*)(&sB[kk][nn]) = *(const float4*)(B + (size_t)(k0 + kk) * 64 + nn);
    }
    __syncthreads();
#pragma unroll 4
    for (int k = 0; k < KC; k += 4) {
      float4 a0 = *(const float4*)(&sA[tr][k]);
      float4 a1 = *(const float4*)(&sA[tr + 16][k]);
      float4 a2 = *(const float4*)(&sA[tr + 32][k]);
      float4 a3 = *(const float4*)(&sA[tr + 48][k]);
#pragma unroll
      for (int u = 0; u < 4; ++u) {
        float4 b = *(const float4*)(&sB[k + u][tc * 4]);
        float av[4] = {((const float*)&a0)[u], ((const float*)&a1)[u],
                       ((const float*)&a2)[u], ((const float*)&a3)[u]};
#pragma unroll
        for (int i = 0; i < 4; ++i) {
          acc[i][0] = fmaf(av[i], b.x, acc[i][0]);
          acc[i][1] = fmaf(av[i], b.y, acc[i][1]);
          acc[i][2] = fmaf(av[i], b.z, acc[i][2]);
          acc[i][3] = fmaf(av[i], b.w, acc[i][3]);
        }
      }
    }
    __syncthreads();
  }

#pragma unroll
  for (int i = 0; i < 4; ++i)
#pragma unroll
    for (int j = 0; j < 4; ++j) sOut[tr + 16 * i][tc * 4 + j] = acc[i][j];
  __syncthreads();

  int wave = tid >> 6, lane = tid & 63;
  size_t nb = (size_t)n * NG;
  for (int t = 0; t < 16; ++t) {
    int rr = wave * 16 + t;
    int node = m0 + rr;
    if (node >= n) break;   // wave-uniform
    float v = 0.f;
    if (lane < 60) {
      v = sOut[rr][lane];
      v += (lane < 20) ? pib[lane] : (lane < 40) ? mub[lane - 20] : lsb[lane - 40];
    }
    float pv = (lane < 20) ? v : -__builtin_inff();
    float mx = pv;
    for (int o = 16; o > 0; o >>= 1) mx = fmaxf(mx, __shfl_down(mx, o, 32));
    mx = __shfl(mx, 0, 32);
    float ev = (lane < 20) ? expf(v - mx) : 0.f;
    float sm = ev;
    for (int o = 16; o > 0; o >>= 1) sm += __shfl_down(sm, o, 32);
    sm = __shfl(sm, 0, 32);
    if (lane < 20)      out[(size_t)node * NG + lane] = ev / sm;
    else if (lane < 40) out[nb + (size_t)node * NG + (lane - 20)] = v;
    else if (lane < 60) out[2 * nb + (size_t)node * NG + (lane - 40)] = v;
  }
}

extern "C" void kernel_launch(void* const* d_in, const int* in_sizes, int n_in,
                              void* d_out, int out_size, void* d_ws, size_t ws_size,
                              hipStream_t stream) {
  const float* x   = (const float*)d_in[0];
  const int*   ei  = (const int*)d_in[1];
  const float* W1  = (const float*)d_in[2];
  const float* b1  = (const float*)d_in[3];
  const float* W2  = (const float*)d_in[4];
  const float* b2  = (const float*)d_in[5];
  const float* piW = (const float*)d_in[6];
  const float* pib = (const float*)d_in[7];
  const float* muW = (const float*)d_in[8];
  const float* mub = (const float*)d_in[9];
  const float* lsW = (const float*)d_in[10];
  const float* lsb = (const float*)d_in[11];
  float* out = (float*)d_out;

  const int N = in_sizes[0] / IN_DIM;
  const int E = in_sizes[1] / 2;
  const int* src = ei;
  const int* dst = ei + E;

  const int NBC  = (N + 255) >> 8;          // 391 coarse bins
  const int nblk = (E + T - 1) / T;         // 782 level-1 blocks
  const int ST   = NBC + 1;

  // workspace layout
  char* p = (char*)d_ws;
  char* regionH = p;                        p += (size_t)N * HID * sizeof(__half);
  __half* h16  = (__half*)regionH;
  char* regionR = p;                        // tmp -> bufB16 -> bufB (sequential reuse)
  size_t szR = (size_t)N * HID * sizeof(float);
  size_t szT = (size_t)E * sizeof(int);
  p += (szR > szT ? szR : szT);
  int*    tmp    = (int*)regionR;
  __half* bufB16 = (__half*)regionR;
  float*  bufB   = (float*)regionR;
  int*   csrc   = (int*)p;                  p += (size_t)E * sizeof(int);
  int*   bofs   = (int*)p;                  p += (size_t)nblk * ST * sizeof(int);
  int*   bintot = (int*)p;                  p += (size_t)MAXB * sizeof(int);
  int*   binbase= (int*)p;                  p += (size_t)MAXB * sizeof(int);
  int*   cnt    = (int*)p;                  p += (size_t)N * sizeof(int);
  int*   offs   = (int*)p;                  p += (size_t)N * sizeof(int);
  float* dis    = (float*)p;                p += (size_t)N * sizeof(float);
  float* W64    = (float*)p;                p += (size_t)128 * 64 * sizeof(float);

  const int NB8 = (N + 7) / 8;       // agg: 2 nodes/wave, 4 waves/block
  const int NBG = (N + 127) / 128;   // mfma gemm: 128 rows/block

  // ---- 8 launches (zero_ints replaces hipMemsetAsync: R12 container-failure suspect) ----
  zero_ints<<<(NBC + 255) / 256, 256, 0, stream>>>(bintot, NBC);
  binsort1<<<nblk, 512, 0, stream>>>(src, dst, tmp, bofs, bintot, NBC, E);
  gemm1_scan<<<NBG + 1, 256, 0, stream>>>(x, W1, h16, N, NBG, bintot, binbase,
                                          NBC, piW, muW, lsW, W64);
  binsort2<<<NBC, 512, 0, stream>>>(tmp, bofs, binbase, csrc, cnt, dis, offs,
                                    NBC, nblk, N);
  agg_kernel<__half><<<NB8, 256, 0, stream>>>(h16, csrc, offs, cnt, dis, b1,
                                              bufB16, N);
  gemm128_mfma_f16<<<NBG, 256, 0, stream>>>(bufB16, W2, h16, N);
  agg_kernel<float><<<NB8, 256, 0, stream>>>(h16, csrc, offs, cnt, dis, b2,
                                             bufB, N);
  heads_fused<<<(N + 63) / 64, 256, 0, stream>>>(bufB, W64, pib, mub, lsb, out, N);
}